// Round 4
// baseline (159.651 us; speedup 1.0000x reference)
//
#include <hip/hip_runtime.h>

// PCEN: x (B=32, T=4000, C=128) fp32.
//   ema[t] = w*x[t] + (1-w)*ema[t-1],  ema[0] = x[0]
//   out = (x / (FLOOR + ema)^alpha + delta)^(1/root) - delta^(1/root)
//
// R3 post-mortem: latency-bound at 3.1 TB/s; compiler collapsed the 20-deep
// scalar pipeline (VGPR=36 -> ~4 outstanding 256B loads/wave).
// R4 design: float4 loads (4 channels/thread, 16 B/lane -> 1 KB/wave/slot),
// NCHUNK=80 x CHUNK=50 keeps 1280 waves (5/CU, exactly balanced).
// Uniform control flow: every chunk runs exactly WARM+CHUNK steps with t<0
// clamped to row 0 — x[0] is an exact fixed point of the EMA, so chunk 0 is
// exact and warm/emit group boundaries are compile-time constants.

#define FLOOR_EPS 1e-12f

constexpr int Bn = 32;
constexpr int Tn = 4000;
constexpr int Cn = 128;
constexpr int NCHUNK = 80;             // chunks along T
constexpr int CHUNK  = Tn / NCHUNK;    // 50
constexpr int WARM   = 200;            // 0.96^200 ~ 2.6e-4 truncation
constexpr int G      = 10;             // pipeline group size
constexpr int NG     = (WARM + CHUNK) / G;  // 25 groups total
constexpr int GW     = WARM / G;            // 20 warm groups (21..24 emit)
constexpr int ROWV   = Cn / 4;         // 32 float4 per (b,t) row
constexpr int CPB    = 2;              // chunks per 64-thread block

__global__ __launch_bounds__(64) void pcen_kernel(
    const float* __restrict__ x,
    const float* __restrict__ alpha_p,
    const float* __restrict__ delta_p,
    const float* __restrict__ root_p,
    const float* __restrict__ w_p,
    float* __restrict__ out)
{
    const int lane = threadIdx.x & 31;        // float4 slot within row
    const int sub  = threadIdx.x >> 5;        // chunk slot within block
    const int j    = blockIdx.x * CPB + sub;  // chunk index 0..79
    const int b    = blockIdx.y;

    // Per-channel parameters (4 channels per thread).
    const int c4 = lane * 4;
    float nal[4], dl[4], oor[4], dr[4], wv[4], om[4];
    #pragma unroll
    for (int q = 0; q < 4; ++q) {
        const int c = c4 + q;
        nal[q] = -fminf(alpha_p[c], 1.0f);
        const float root = fmaxf(root_p[c], 1.0f);
        oor[q] = 1.0f / root;
        dl[q]  = delta_p[c];
        dr[q]  = __builtin_exp2f(oor[q] * __builtin_log2f(dl[q]));
        wv[q]  = fminf(fmaxf(w_p[c], 0.0f), 1.0f);
        om[q]  = 1.0f - wv[q];
    }

    const int start = j * CHUNK;
    const int t0    = start - WARM;           // may be negative (clamped loads)

    const float4* __restrict__ xp =
        (const float4*)(x + (size_t)b * Tn * Cn) + lane;
    float4* __restrict__ op =
        (float4*)(out + (size_t)b * Tn * Cn) + lane;

    float4 buf[2][G];
    float acc[4];

    auto loadg = [&](float4* dst, int g) {
        const int tg = t0 + g * G;
        #pragma unroll
        for (int k = 0; k < G; ++k) {
            int t = tg + k;
            t = t < 0 ? 0 : t;                // row-0 clamp: EMA fixed point
            dst[k] = xp[(size_t)t * ROWV];
        }
    };
    auto warmg = [&](const float4* cur) {
        #pragma unroll
        for (int k = 0; k < G; ++k) {
            const float4 v = cur[k];
            const float xv[4] = {v.x, v.y, v.z, v.w};
            #pragma unroll
            for (int q = 0; q < 4; ++q)
                acc[q] = fmaf(om[q], acc[q], wv[q] * xv[q]);
        }
    };
    auto emitg = [&](const float4* cur, int g) {
        const int tg = t0 + g * G;            // >= start >= 0 for g >= GW
        #pragma unroll
        for (int k = 0; k < G; ++k) {
            const float4 v = cur[k];
            const float xv[4] = {v.x, v.y, v.z, v.w};
            float r[4];
            #pragma unroll
            for (int q = 0; q < 4; ++q) {
                acc[q] = fmaf(om[q], acc[q], wv[q] * xv[q]);
                const float l  = __builtin_log2f(FLOOR_EPS + acc[q]);
                const float t1 = xv[q] * __builtin_exp2f(nal[q] * l);
                r[q] = __builtin_exp2f(oor[q] * __builtin_log2f(t1 + dl[q])) - dr[q];
            }
            op[(size_t)(tg + k) * ROWV] = make_float4(r[0], r[1], r[2], r[3]);
        }
    };

    // Prologue: group 0; init acc from its first element (exact: first fma
    // then reproduces x[t0'] as required by ema-init semantics).
    loadg(buf[0], 0);
    {
        const float4 v0 = buf[0][0];
        acc[0] = v0.x; acc[1] = v0.y; acc[2] = v0.z; acc[3] = v0.w;
    }

    // Warm phase: groups 0..GW-1, double-buffered, pair-unrolled so buffer
    // indices are compile-time. Invariant: group g lives in buf[g&1].
    for (int g = 0; g < GW; g += 2) {
        loadg(buf[1], g + 1);
        warmg(buf[0]);
        loadg(buf[0], g + 2);   // at g=GW-2 this preloads group GW (emit)
        warmg(buf[1]);
    }

    // Emit phase: groups GW..NG-1 (compile-time unrolled; parity continues).
    #pragma unroll
    for (int e = GW; e < NG; ++e) {
        if (e + 1 < NG) loadg(buf[(e + 1) & 1], e + 1);
        emitg(buf[e & 1], e);
    }
}

extern "C" void kernel_launch(void* const* d_in, const int* in_sizes, int n_in,
                              void* d_out, int out_size, void* d_ws, size_t ws_size,
                              hipStream_t stream) {
    const float* x     = (const float*)d_in[0];
    const float* alpha = (const float*)d_in[1];
    const float* delta = (const float*)d_in[2];
    const float* root  = (const float*)d_in[3];
    const float* ew    = (const float*)d_in[4];
    float* out = (float*)d_out;

    dim3 grid(NCHUNK / CPB, Bn, 1);   // 40 x 32 = 1280 blocks = 5/CU exact
    pcen_kernel<<<grid, 64, 0, stream>>>(x, alpha, delta, root, ew, out);
}

// Round 6
// 132.796 us; speedup vs baseline: 1.2022x; 1.2022x over previous
//
#include <hip/hip_runtime.h>

// PCEN: x (B=32, T=4000, C=128) fp32.
//   ema[t] = w*x[t] + (1-w)*ema[t-1],  ema[0] = x[0]
//   out = (x / (FLOOR + ema)^alpha + delta)^(1/root) - delta^(1/root)
//
// R5 design (exact two-pass chunked linear-recurrence scan):
//   K1: per chunk j, S_j = sum_i w(1-w)^{L-1-i} x[i]   (local sum, init 0)
//   K2: per (b,c), scan e_{j+1} = A e_j + S_j, A=(1-w)^L (Kogge-Stone, 1 wave)
//   K3: per chunk j, run recurrence from exact e_j + transcendental epilogue
// S_j / E_j are staged INSIDE d_out (rows j*CHUNK+1 / j*CHUNK of chunk j's own
// output region, overwritten by K3 after it reads them) -> no workspace.
// R5 bug: K2 launched with 64 waves instead of 4096 (one per (b,c)) ->
// most chunks started from memset-0 state. Fixed: 1024 blocks x 256.

#define FLOOR_EPS 1e-12f

constexpr int Bn = 32;
constexpr int Tn = 4000;
constexpr int Cn = 128;
constexpr int NCHUNK = 125;          // 125 * 32 = 4000
constexpr int CHUNK  = 32;

// ---------------- K1: local weighted sums ----------------
__global__ __launch_bounds__(Cn) void k1_localsum(
    const float* __restrict__ x,
    const float* __restrict__ w_p,
    float* __restrict__ out)
{
    const int c = threadIdx.x;
    const int j = blockIdx.x;
    const int b = blockIdx.y;
    const float w   = fminf(fmaxf(w_p[c], 0.0f), 1.0f);
    const float omw = 1.0f - w;

    const float* __restrict__ xp = x + ((size_t)b * Tn + (size_t)j * CHUNK) * Cn + c;
    float s = 0.0f;
    #pragma unroll
    for (int k = 0; k < CHUNK; ++k)           // loads address-independent:
        s = fmaf(omw, s, w * xp[(size_t)k * Cn]);  // compiler clusters them
    out[((size_t)b * Tn + (size_t)j * CHUNK + 1) * Cn + c] = s;  // S_j row
}

// ---------------- K2: chunk-state scan (one wave per (b,c)) ----------------
__global__ __launch_bounds__(256) void k2_scan(
    const float* __restrict__ x,
    const float* __restrict__ w_p,
    float* __restrict__ out)
{
    const int wid  = (blockIdx.x * 256 + threadIdx.x) >> 6;  // 0..4095
    const int lane = threadIdx.x & 63;
    const int b = wid >> 7;        // 0..31
    const int c = wid & 127;       // 0..127

    const float w   = fminf(fmaxf(w_p[c], 0.0f), 1.0f);
    const float omw = 1.0f - w;
    // A = omw^CHUNK  (omw=0 -> log2=-inf -> A=0, correct; omw=1 -> A=1)
    const float A = __builtin_exp2f((float)CHUNK * __builtin_log2f(omw));

    const float* __restrict__ sb = out + (size_t)b * Tn * Cn + c;
    float* __restrict__ eb       = out + (size_t)b * Tn * Cn + c;

    // segment 1: chunks j = lane (0..63); segment 2: j = 64+lane (<125)
    float s1 = sb[((size_t)lane * CHUNK + 1) * Cn];
    float a1 = A;
    const int j2 = 64 + lane;
    float s2 = (j2 < NCHUNK) ? sb[((size_t)j2 * CHUNK + 1) * Cn] : 0.0f;
    float a2 = (j2 < NCHUNK) ? A : 1.0f;

    // inclusive Kogge-Stone scan of affine transforms (a,s): e -> a*e + s
    // compose(prev p, cur q) = (q.a*p.a, q.a*p.s + q.s)
    #pragma unroll
    for (int r = 1; r < 64; r <<= 1) {
        float ts = __shfl_up(s1, r, 64);
        float ta = __shfl_up(a1, r, 64);
        if (lane >= r) { s1 = fmaf(a1, ts, s1); a1 *= ta; }
        ts = __shfl_up(s2, r, 64);
        ta = __shfl_up(a2, r, 64);
        if (lane >= r) { s2 = fmaf(a2, ts, s2); a2 *= ta; }
    }

    const float e0 = x[(size_t)b * Tn * Cn + c];          // ema init = x[b,0,c]
    const float E1 = fmaf(a1, e0, s1);                    // E_{lane+1}
    const float E64 = __shfl(E1, 63, 64);                 // carry into segment 2
    const float E2 = fmaf(a2, E64, s2);                   // E_{65+lane}

    if (lane == 0) eb[0] = e0;                            // E_0 (row 0)
    eb[(size_t)(lane + 1) * CHUNK * Cn] = E1;             // E_1..E_64
    if (lane + 65 < NCHUNK)
        eb[(size_t)(lane + 65) * CHUNK * Cn] = E2;        // E_65..E_124
}

// ---------------- K3: apply recurrence + epilogue ----------------
__global__ __launch_bounds__(Cn) void k3_apply(
    const float* __restrict__ x,
    const float* __restrict__ alpha_p,
    const float* __restrict__ delta_p,
    const float* __restrict__ root_p,
    const float* __restrict__ w_p,
    float* __restrict__ out)
{
    const int c = threadIdx.x;
    const int j = blockIdx.x;
    const int b = blockIdx.y;

    const float alpha  = fminf(alpha_p[c], 1.0f);
    const float root   = fmaxf(root_p[c], 1.0f);
    const float delta  = delta_p[c];
    const float oor    = 1.0f / root;
    const float droot  = __builtin_exp2f(oor * __builtin_log2f(delta));
    const float nalpha = -alpha;
    const float w      = fminf(fmaxf(w_p[c], 0.0f), 1.0f);
    const float omw    = 1.0f - w;

    const size_t base = ((size_t)b * Tn + (size_t)j * CHUNK) * Cn + c;
    const float* __restrict__ xp = x + base;
    float* __restrict__ op = out + base;

    float acc = op[0];   // exact E_j written by K2 (this block's own region)

    // two half-chunk phases: 16 preloaded x values each (keeps VGPR moderate,
    // 16 independent loads in flight per phase)
    #pragma unroll
    for (int h = 0; h < 2; ++h) {
        float xv[16];
        const int t0 = h * 16;
        #pragma unroll
        for (int k = 0; k < 16; ++k) xv[k] = xp[(size_t)(t0 + k) * Cn];
        #pragma unroll
        for (int k = 0; k < 16; ++k) {
            acc = fmaf(omw, acc, w * xv[k]);
            const float l  = __builtin_log2f(FLOOR_EPS + acc);
            const float t1 = xv[k] * __builtin_exp2f(nalpha * l);
            op[(size_t)(t0 + k) * Cn] =
                __builtin_exp2f(oor * __builtin_log2f(t1 + delta)) - droot;
        }
    }
}

extern "C" void kernel_launch(void* const* d_in, const int* in_sizes, int n_in,
                              void* d_out, int out_size, void* d_ws, size_t ws_size,
                              hipStream_t stream) {
    const float* x     = (const float*)d_in[0];
    const float* alpha = (const float*)d_in[1];
    const float* delta = (const float*)d_in[2];
    const float* root  = (const float*)d_in[3];
    const float* ew    = (const float*)d_in[4];
    float* out = (float*)d_out;

    dim3 grid(NCHUNK, Bn, 1);                     // 4000 blocks, 8000 waves
    k1_localsum<<<grid, Cn, 0, stream>>>(x, ew, out);
    // one wave per (b,c): 32*128 = 4096 waves = 1024 blocks x 256 threads
    k2_scan<<<dim3((Bn * Cn * 64) / 256), 256, 0, stream>>>(x, ew, out);
    k3_apply<<<grid, Cn, 0, stream>>>(x, alpha, delta, root, ew, out);
}